// Round 5
// baseline (382.560 us; speedup 1.0000x reference)
//
#include <hip/hip_runtime.h>
#include <hip/hip_bf16.h>

#define N_NODES 100000
#define N_EDGES 1000000
// P row layout per node (f16): [A' = Wc1a@z + b_c1 (128)] [B = Wc1b@z (128)]
//                              [Y = Wb@z (128)]            [Zh = f16(z) (128)]
#define PROW 512
#define NCHUNK (N_NODES / 16)   // 6250
#define NB (N_EDGES / 16)       // 62500

typedef float f32x4 __attribute__((ext_vector_type(4)));
typedef _Float16 f16x8 __attribute__((ext_vector_type(8)));
typedef _Float16 f16x2 __attribute__((ext_vector_type(2)));

__device__ inline f16x8 pack8(float4 a, float4 b) {
    f16x8 o;
    o[0] = (_Float16)a.x; o[1] = (_Float16)a.y; o[2] = (_Float16)a.z; o[3] = (_Float16)a.w;
    o[4] = (_Float16)b.x; o[5] = (_Float16)b.y; o[6] = (_Float16)b.z; o[7] = (_Float16)b.w;
    return o;
}
__device__ inline void mfma16(f32x4& acc, f16x8 a, f16x8 b) {
    acc = __builtin_amdgcn_mfma_f32_16x16x32_f16(a, b, acc, 0, 0, 0);
}
__device__ inline float fdot2(f16x8 a, f16x8 b, int j2, float c) {
    f16x2 pa = { a[2 * j2], a[2 * j2 + 1] };
    f16x2 pb = { b[2 * j2], b[2 * j2 + 1] };
    return __builtin_amdgcn_fdot2(pa, pb, c, false);
}

// ---- precompute: each block stages a 16-node z-chunk in LDS once; 4 waves cover
// ---- 6 GEMM col-tiles (cols 0..383) + 2 Zh copy halves (cols 384..511).
__global__ __launch_bounds__(256) void precomp_kernel(
    const float* __restrict__ z, const float* __restrict__ w_c1,
    const float* __restrict__ b_c1, const float* __restrict__ w_b,
    _Float16* __restrict__ P)
{
    __shared__ float zt[16][132];   // +4 pad: 2-way LDS banks on f32x4 reads
    const int tid = threadIdx.x;
    const int lane = tid & 63;
    const int w = tid >> 6;
    const int r = lane & 15, g = lane >> 4;

    for (int nb = blockIdx.x; nb < NCHUNK; nb += gridDim.x) {
        // stage z[16][128] (each thread 2 float4s, coalesced)
#pragma unroll
        for (int i = tid; i < 512; i += 256) {
            const int row = i >> 5, c4 = (i & 31) * 4;
            float4 v = *reinterpret_cast<const float4*>(
                z + (size_t)(nb * 16 + row) * 128 + c4);
            *reinterpret_cast<float4*>(&zt[row][c4]) = v;
        }
        __syncthreads();

        // two tasks per wave: t0 = w (GEMM ct), t1 = w+4 (GEMM ct 4,5 or Zh half)
#pragma unroll
        for (int task = 0; task < 2; ++task) {
            const int t = w + task * 4;
            if (t < 6) {
                const int ct = t;
                // load B-fragments for this col-tile (L2-hot, reload per chunk)
                f16x8 bw[4][4];
#pragma unroll
                for (int nt = 0; nt < 4; ++nt) {
                    const int c = ct * 64 + nt * 16 + r;
                    const float* wrow;
                    if (c < 128)       wrow = w_c1 + (size_t)c * 256;
                    else if (c < 256)  wrow = w_c1 + (size_t)(c - 128) * 256 + 128;
                    else               wrow = w_b + (size_t)(c - 256) * 128;
#pragma unroll
                    for (int kk = 0; kk < 4; ++kk) {
                        const int k0 = kk * 32 + g * 8;
                        float4 f0 = *reinterpret_cast<const float4*>(wrow + k0);
                        float4 f1 = *reinterpret_cast<const float4*>(wrow + k0 + 4);
                        bw[nt][kk] = pack8(f0, f1);
                    }
                }
                float bc1v[4] = {0.f, 0.f, 0.f, 0.f};
                if (ct < 2) {
#pragma unroll
                    for (int nt = 0; nt < 4; ++nt)
                        bc1v[nt] = b_c1[ct * 64 + nt * 16 + r];
                }
                f32x4 acc[4] = {};
#pragma unroll
                for (int kk = 0; kk < 4; ++kk) {
                    const int k0 = kk * 32 + g * 8;
                    float4 z0 = *reinterpret_cast<const float4*>(&zt[r][k0]);
                    float4 z1 = *reinterpret_cast<const float4*>(&zt[r][k0 + 4]);
                    f16x8 a = pack8(z0, z1);
#pragma unroll
                    for (int nt = 0; nt < 4; ++nt) mfma16(acc[nt], a, bw[nt][kk]);
                }
#pragma unroll
                for (int nt = 0; nt < 4; ++nt) {
#pragma unroll
                    for (int rr = 0; rr < 4; ++rr) {
                        const int node = nb * 16 + g * 4 + rr;
                        const int col = ct * 64 + nt * 16 + r;
                        P[(size_t)node * PROW + col] = (_Float16)(acc[nt][rr] + bc1v[nt]);
                    }
                }
            } else {
                // Zh copy half h = t-6: rows r, cols h*64 + g*16 .. +15
                const int h = t - 6;
                const int c0 = h * 64 + g * 16;
                const int node_r = nb * 16 + r;
                float4 f0 = *reinterpret_cast<const float4*>(&zt[r][c0]);
                float4 f1 = *reinterpret_cast<const float4*>(&zt[r][c0 + 4]);
                float4 f2 = *reinterpret_cast<const float4*>(&zt[r][c0 + 8]);
                float4 f3 = *reinterpret_cast<const float4*>(&zt[r][c0 + 12]);
                _Float16* op = P + (size_t)node_r * PROW + 384 + c0;
                *reinterpret_cast<f16x8*>(op) = pack8(f0, f1);
                *reinterpret_cast<f16x8*>(op + 8) = pack8(f2, f3);
            }
        }
        __syncthreads();   // before next chunk overwrites zt
    }
}

// ---------------- counting sort by dst ----------------
__global__ __launch_bounds__(256) void zero_kernel(int* __restrict__ counts) {
    const int i = blockIdx.x * 256 + threadIdx.x;
    if (i < N_NODES) counts[i] = 0;
}
__global__ __launch_bounds__(256) void hist_kernel(const int* __restrict__ edge,
                                                   int* __restrict__ counts) {
    for (int e = blockIdx.x * 256 + threadIdx.x; e < N_EDGES; e += gridDim.x * 256)
        atomicAdd(&counts[edge[2 * e + 1]], 1);
}
// scanA: per-1024-block exclusive scan; bsum[b] = block total
__global__ __launch_bounds__(1024) void scanA_kernel(const int* __restrict__ counts,
                                                     int* __restrict__ offs,
                                                     int* __restrict__ bsum) {
    __shared__ int buf[1024];
    const int tid = threadIdx.x;
    const int i = blockIdx.x * 1024 + tid;
    const int v = (i < N_NODES) ? counts[i] : 0;
    buf[tid] = v;
    __syncthreads();
    for (int off = 1; off < 1024; off <<= 1) {
        const int t = (tid >= off) ? buf[tid - off] : 0;
        __syncthreads();
        buf[tid] += t;
        __syncthreads();
    }
    if (i < N_NODES) offs[i] = buf[tid] - v;   // exclusive within block
    if (tid == 1023) bsum[blockIdx.x] = buf[1023];
}
__global__ void scanB_kernel(int* __restrict__ bsum, int nblk) {
    if (threadIdx.x == 0 && blockIdx.x == 0) {
        int carry = 0;
        for (int j = 0; j < nblk; ++j) { int t = bsum[j]; bsum[j] = carry; carry += t; }
    }
}
__global__ __launch_bounds__(1024) void scanC_kernel(int* __restrict__ offs,
                                                     const int* __restrict__ bsum) {
    const int i = blockIdx.x * 1024 + threadIdx.x;
    if (i < N_NODES) offs[i] += bsum[blockIdx.x];
}
__global__ __launch_bounds__(256) void scatter_kernel(const int* __restrict__ edge,
                                                      int* __restrict__ offs,
                                                      int2* __restrict__ sE,
                                                      int* __restrict__ sOrig) {
    for (int e = blockIdx.x * 256 + threadIdx.x; e < N_EDGES; e += gridDim.x * 256) {
        const int s = edge[2 * e], d = edge[2 * e + 1];
        const int pos = atomicAdd(&offs[d], 1);
        sE[pos] = make_int2(s, d);
        sOrig[pos] = e;
    }
}

// ---------------- main edge kernel: 16 edges/wave, unified lane layout ----------------
// lane = g*16 + r : edge = b*16 + r, k-slice = {kk*32 + g*8 .. +8} for kk=0..3.
// Contiguous per-wave chunks (preserves dst-sorted locality). orig==null -> direct out.
__global__ __launch_bounds__(256) void edge_kernel(
    const int2* __restrict__ eArr, const int* __restrict__ orig,
    const _Float16* __restrict__ P,
    const float* __restrict__ w_h1, const float* __restrict__ b_h1,
    const float* __restrict__ w_h2, const float* __restrict__ b_h2,
    const float* __restrict__ w_c2, const float* __restrict__ b_c2,
    const float* __restrict__ b_b, const float* __restrict__ sw,
    float* __restrict__ out)
{
    __shared__ f16x8 bwlds[1024];   // W_h1 B-fragments: idx=(nt*4+kk)*64 + g*16 + r

    const int tid = threadIdx.x;
    for (int e = tid; e < 1024; e += 256) {
        const int r_ = e & 15, g_ = (e >> 4) & 3, kkf = (e >> 6) & 3, ntf = e >> 8;
        const float* wr = w_h1 + (size_t)(ntf * 16 + r_) * 128 + kkf * 32 + g_ * 8;
        float4 f0 = *reinterpret_cast<const float4*>(wr);
        float4 f1 = *reinterpret_cast<const float4*>(wr + 4);
        bwlds[e] = pack8(f0, f1);
    }
    __syncthreads();

    const int lane = tid & 63;
    const int r = lane & 15, g = lane >> 4;

    const float s0 = sw[0], s1 = sw[1], s2 = sw[2];
    const float mx = fmaxf(s0, fmaxf(s1, s2));
    const float e0 = __expf(s0 - mx), e1 = __expf(s1 - mx), e2 = __expf(s2 - mx);
    const float inv = 1.0f / (e0 + e1 + e2);
    const float W0 = e0 * inv, W1 = e1 * inv, W2 = e2 * inv;
    const float cbias = W0 * b_h2[0] + W1 * b_c2[0] + W2 * b_b[0];

    float bh1v[4], wh2v[4];
#pragma unroll
    for (int nt = 0; nt < 4; ++nt) {
        bh1v[nt] = b_h1[nt * 16 + r];
        wh2v[nt] = w_h2[nt * 16 + r] * W0;   // W0 folded
    }
    f16x8 wc2r[4];
#pragma unroll
    for (int kk = 0; kk < 4; ++kk) {
        const int k0 = kk * 32 + g * 8;
        float4 f0 = *reinterpret_cast<const float4*>(w_c2 + k0);
        float4 f1 = *reinterpret_cast<const float4*>(w_c2 + k0 + 4);
        f0.x *= W1; f0.y *= W1; f0.z *= W1; f0.w *= W1;
        f1.x *= W1; f1.y *= W1; f1.z *= W1; f1.w *= W1;
        wc2r[kk] = pack8(f0, f1);   // W1 folded
    }
    const f16x8* myb = bwlds + g * 16 + r;

    const int gwid = (blockIdx.x * blockDim.x + tid) >> 6;
    const int nW = (gridDim.x * blockDim.x) >> 6;
    const int per = (NB + nW - 1) / nW;
    const int b0 = gwid * per;
    const int b1 = min(b0 + per, NB);
    const int rsel = r & 3;
    const int srcl = ((r >> 2) << 4) | r;

    int b = b0;
    int2 sd = make_int2(0, 0);
    int ov = 0;
    if (b < b1) {
        sd = eArr[b * 16 + r];
        ov = orig ? orig[b * 16 + r] : b * 16 + r;
    }

    for (; b < b1; ++b) {
        int2 sdn = sd; int ovn = ov;
        if (b + 1 < b1) {
            sdn = eArr[(b + 1) * 16 + r];
            ovn = orig ? orig[(b + 1) * 16 + r] : (b + 1) * 16 + r;
        }

        const _Float16* ps = P + (size_t)sd.x * PROW;
        const _Float16* pd = P + (size_t)sd.y * PROW;

        // issue all 20 gathers up front (2 bases, static offsets)
        f16x8 av[4], bv[4], yv[4], zs[4], zd[4];
#pragma unroll
        for (int kk = 0; kk < 4; ++kk) {
            const int off = kk * 32 + g * 8;
            av[kk] = *reinterpret_cast<const f16x8*>(ps + off);         // A'[src]
            bv[kk] = *reinterpret_cast<const f16x8*>(pd + 128 + off);   // B[dst]
            yv[kk] = *reinterpret_cast<const f16x8*>(pd + 256 + off);   // Y[dst]
            zs[kk] = *reinterpret_cast<const f16x8*>(ps + 384 + off);   // Zh[src]
            zd[kk] = *reinterpret_cast<const f16x8*>(pd + 384 + off);   // Zh[dst]
        }

        // score1 via MFMA
        f32x4 acc[4] = {};
#pragma unroll
        for (int kk = 0; kk < 4; ++kk) {
            f16x8 a = zs[kk] * zd[kk];
            mfma16(acc[0], a, myb[(0 * 4 + kk) * 64]);
            mfma16(acc[1], a, myb[(1 * 4 + kk) * 64]);
            mfma16(acc[2], a, myb[(2 * 4 + kk) * 64]);
            mfma16(acc[3], a, myb[(3 * 4 + kk) * 64]);
        }
        float t4[4];
#pragma unroll
        for (int rr = 0; rr < 4; ++rr) {
            float s = 0.f;
#pragma unroll
            for (int nt = 0; nt < 4; ++nt)
                s = fmaf(fmaxf(acc[nt][rr] + bh1v[nt], 0.f), wh2v[nt], s);
            t4[rr] = s;
        }
#pragma unroll
        for (int mask = 1; mask <= 8; mask <<= 1) {
#pragma unroll
            for (int rr = 0; rr < 4; ++rr)
                t4[rr] += __shfl_xor(t4[rr], mask, 16);
        }
        float u = t4[0];
        if (rsel == 1) u = t4[1];
        if (rsel == 2) u = t4[2];
        if (rsel == 3) u = t4[3];
        const float sc1w = __shfl(u, srcl, 64);

        // score2 & score3
        float sA = 0.f, sB = 0.f;
#pragma unroll
        for (int kk = 0; kk < 4; ++kk) {
            f16x8 s = av[kk] + bv[kk];
            s = __builtin_elementwise_max(s, (f16x8)(_Float16)0.f);
#pragma unroll
            for (int j2 = 0; j2 < 4; ++j2) {
                sA = fdot2(s, wc2r[kk], j2, sA);
                sB = fdot2(zs[kk], yv[kk], j2, sB);
            }
        }
        sA += __shfl_xor(sA, 16, 64);
        sA += __shfl_xor(sA, 32, 64);
        sB += __shfl_xor(sB, 16, 64);
        sB += __shfl_xor(sB, 32, 64);

        const float res = sc1w + sA + fmaf(W2, sB, cbias);
        if (lane < 16) out[ov] = res;
        sd = sdn; ov = ovn;
    }
}

// ---------------- fallback: fused wave-per-edge, no workspace ----------------
__global__ __launch_bounds__(256) void fused_fallback(
    const float* __restrict__ z, const int* __restrict__ edge,
    const float* __restrict__ w_h1, const float* __restrict__ b_h1,
    const float* __restrict__ w_h2, const float* __restrict__ b_h2,
    const float* __restrict__ w_c1, const float* __restrict__ b_c1,
    const float* __restrict__ w_c2, const float* __restrict__ b_c2,
    const float* __restrict__ w_b, const float* __restrict__ b_b,
    const float* __restrict__ sw, float* __restrict__ out)
{
    __shared__ float zbuf[4][256];
    const int lane = threadIdx.x & 63;
    const int w = threadIdx.x >> 6;
    const int gw = blockIdx.x * 4 + w;
    const int nw = gridDim.x * 4;

    const float s0 = sw[0], s1 = sw[1], s2 = sw[2];
    const float mx = fmaxf(s0, fmaxf(s1, s2));
    const float e0 = __expf(s0 - mx), e1 = __expf(s1 - mx), e2 = __expf(s2 - mx);
    const float inv = 1.0f / (e0 + e1 + e2);
    const float W0 = e0 * inv, W1 = e1 * inv, W2 = e2 * inv;
    const float cbias = W0 * b_h2[0] + W1 * b_c2[0] + W2 * b_b[0];

    for (int e = gw; e < N_EDGES; e += nw) {
        const int src = edge[2 * e], dst = edge[2 * e + 1];
        const float zs0 = z[(size_t)src * 128 + lane];
        const float zs1 = z[(size_t)src * 128 + 64 + lane];
        const float zd0 = z[(size_t)dst * 128 + lane];
        const float zd1 = z[(size_t)dst * 128 + 64 + lane];
        zbuf[w][lane] = zs0; zbuf[w][64 + lane] = zs1;
        zbuf[w][128 + lane] = zd0; zbuf[w][192 + lane] = zd1;
        asm volatile("s_waitcnt lgkmcnt(0)" ::: "memory");

        float h = 0.f;
        const float* whr = w_h1 + (size_t)lane * 128;
        for (int d = 0; d < 128; ++d)
            h = fmaf(zbuf[w][d] * zbuf[w][128 + d], whr[d], h);
        float sc1 = fmaxf(h + b_h1[lane], 0.f) * w_h2[lane];

        float c0 = 0.f, c1 = 0.f;
        const float* w0r = w_c1 + (size_t)lane * 256;
        const float* w1r = w_c1 + (size_t)(lane + 64) * 256;
        for (int d = 0; d < 256; ++d) {
            const float cat = zbuf[w][d];
            c0 = fmaf(cat, w0r[d], c0);
            c1 = fmaf(cat, w1r[d], c1);
        }
        float sc2 = fmaxf(c0 + b_c1[lane], 0.f) * w_c2[lane]
                  + fmaxf(c1 + b_c1[lane + 64], 0.f) * w_c2[lane + 64];

        float t0 = 0.f, t1 = 0.f;
        const float* wb0 = w_b + (size_t)lane * 128;
        const float* wb1 = w_b + (size_t)(lane + 64) * 128;
        for (int f = 0; f < 128; ++f) {
            const float zdf = zbuf[w][128 + f];
            t0 = fmaf(wb0[f], zdf, t0);
            t1 = fmaf(wb1[f], zdf, t1);
        }
        float sc3 = zs0 * t0 + zs1 * t1;

        float v = fmaf(W0, sc1, fmaf(W1, sc2, W2 * sc3));
#pragma unroll
        for (int m = 1; m < 64; m <<= 1) v += __shfl_xor(v, m, 64);
        if (lane == 0) out[e] = v + cbias;
    }
}

extern "C" void kernel_launch(void* const* d_in, const int* in_sizes, int n_in,
                              void* d_out, int out_size, void* d_ws, size_t ws_size,
                              hipStream_t stream)
{
    const float* z    = (const float*)d_in[0];
    const int*   edge = (const int*)d_in[1];
    const float* w_h1 = (const float*)d_in[2];
    const float* b_h1 = (const float*)d_in[3];
    const float* w_h2 = (const float*)d_in[4];
    const float* b_h2 = (const float*)d_in[5];
    const float* w_c1 = (const float*)d_in[6];
    const float* b_c1 = (const float*)d_in[7];
    const float* w_c2 = (const float*)d_in[8];
    const float* b_c2 = (const float*)d_in[9];
    const float* w_b  = (const float*)d_in[10];
    const float* b_b  = (const float*)d_in[11];
    const float* sw   = (const float*)d_in[12];
    float* outp = (float*)d_out;

    // ws layout
    const size_t szP     = (size_t)N_NODES * PROW * sizeof(_Float16);  // 102,400,000
    const size_t szCnt   = (size_t)N_NODES * sizeof(int);              //     400,000
    const size_t szBsum  = 512;                                        // 98 ints, padded
    const size_t szSE    = (size_t)N_EDGES * sizeof(int2);             //   8,000,000
    const size_t szSO    = (size_t)N_EDGES * sizeof(int);              //   4,000,000
    const size_t needP    = szP;
    const size_t needSort = szP + szCnt + szCnt + szBsum + szSE + szSO;

    if (ws_size >= needP) {
        char* wsb = (char*)d_ws;
        _Float16* P = (_Float16*)wsb;
        hipLaunchKernelGGL(precomp_kernel, dim3(1024), dim3(256), 0, stream,
                           z, w_c1, b_c1, w_b, P);
        if (ws_size >= needSort) {
            int*  counts = (int*)(wsb + szP);
            int*  offs   = (int*)(wsb + szP + szCnt);
            int*  bsum   = (int*)(wsb + szP + 2 * szCnt);
            int2* sE     = (int2*)(wsb + szP + 2 * szCnt + szBsum);
            int*  sOrig  = (int*)(wsb + szP + 2 * szCnt + szBsum + szSE);
            const int nblk = (N_NODES + 1023) / 1024;   // 98
            hipLaunchKernelGGL(zero_kernel, dim3((N_NODES + 255) / 256), dim3(256),
                               0, stream, counts);
            hipLaunchKernelGGL(hist_kernel, dim3(2048), dim3(256), 0, stream,
                               edge, counts);
            hipLaunchKernelGGL(scanA_kernel, dim3(nblk), dim3(1024), 0, stream,
                               counts, offs, bsum);
            hipLaunchKernelGGL(scanB_kernel, dim3(1), dim3(64), 0, stream, bsum, nblk);
            hipLaunchKernelGGL(scanC_kernel, dim3(nblk), dim3(1024), 0, stream,
                               offs, bsum);
            hipLaunchKernelGGL(scatter_kernel, dim3(2048), dim3(256), 0, stream,
                               edge, offs, sE, sOrig);
            hipLaunchKernelGGL(edge_kernel, dim3(1024), dim3(256), 0, stream,
                               sE, sOrig, P, w_h1, b_h1, w_h2, b_h2, w_c2, b_c2,
                               b_b, sw, outp);
        } else {
            hipLaunchKernelGGL(edge_kernel, dim3(1024), dim3(256), 0, stream,
                               (const int2*)edge, (const int*)nullptr, P,
                               w_h1, b_h1, w_h2, b_h2, w_c2, b_c2, b_b, sw, outp);
        }
    } else {
        hipLaunchKernelGGL(fused_fallback, dim3(4096), dim3(256), 0, stream,
                           z, edge, w_h1, b_h1, w_h2, b_h2, w_c1, b_c1,
                           w_c2, b_c2, w_b, b_b, sw, outp);
    }
}

// Round 6
// 296.766 us; speedup vs baseline: 1.2891x; 1.2891x over previous
//
#include <hip/hip_runtime.h>
#include <hip/hip_bf16.h>

#define N_NODES 100000
#define N_EDGES 1000000
// P row layout per node (f16): [A' = Wc1a@z + b_c1 (128)] [B = Wc1b@z (128)]
//                              [Y = Wb@z (128)]            [Zh = f16(z) (128)]
#define PROW 512
#define NB (N_EDGES / 16)       // 62500

typedef float f32x4 __attribute__((ext_vector_type(4)));
typedef _Float16 f16x8 __attribute__((ext_vector_type(8)));
typedef _Float16 f16x2 __attribute__((ext_vector_type(2)));

__device__ inline f16x8 pack8(float4 a, float4 b) {
    f16x8 o;
    o[0] = (_Float16)a.x; o[1] = (_Float16)a.y; o[2] = (_Float16)a.z; o[3] = (_Float16)a.w;
    o[4] = (_Float16)b.x; o[5] = (_Float16)b.y; o[6] = (_Float16)b.z; o[7] = (_Float16)b.w;
    return o;
}
__device__ inline void mfma16(f32x4& acc, f16x8 a, f16x8 b) {
    acc = __builtin_amdgcn_mfma_f32_16x16x32_f16(a, b, acc, 0, 0, 0);
}
__device__ inline float fdot2(f16x8 a, f16x8 b, int j2, float c) {
    f16x2 pa = { a[2 * j2], a[2 * j2 + 1] };
    f16x2 pb = { b[2 * j2], b[2 * j2 + 1] };
    return __builtin_amdgcn_fdot2(pa, pb, c, false);
}

// ---- precompute (round-4 structure: B-frags hoisted OUT of node loop) ----
// P cols 0..383 = Z @ W_all^T ; Zh (cols 384..511) fused into ct==0 walkers.
__global__ __launch_bounds__(256) void precomp_kernel(
    const float* __restrict__ z, const float* __restrict__ w_c1,
    const float* __restrict__ b_c1, const float* __restrict__ w_b,
    _Float16* __restrict__ P)
{
    const int lane = threadIdx.x & 63;
    const int r = lane & 15, g = lane >> 4;
    const int wid = blockIdx.x * 4 + (threadIdx.x >> 6);
    const int ct = wid % 6;          // 6 GEMM col-tiles of 64 over 384 P columns
    const int walker = wid / 6;
    const int nWalk = (gridDim.x * 4) / 6;
    if (walker >= nWalk) return;

    f16x8 bw[4][4];                  // loaded ONCE per kernel
#pragma unroll
    for (int nt = 0; nt < 4; ++nt) {
        const int c = ct * 64 + nt * 16 + r;
        const float* wrow;
        if (c < 128)       wrow = w_c1 + (size_t)c * 256;               // Wc1a row
        else if (c < 256)  wrow = w_c1 + (size_t)(c - 128) * 256 + 128; // Wc1b row
        else               wrow = w_b + (size_t)(c - 256) * 128;        // Wb row
#pragma unroll
        for (int kk = 0; kk < 4; ++kk) {
            const int k0 = kk * 32 + g * 8;
            float4 f0 = *reinterpret_cast<const float4*>(wrow + k0);
            float4 f1 = *reinterpret_cast<const float4*>(wrow + k0 + 4);
            bw[nt][kk] = pack8(f0, f1);
        }
    }
    float bc1v[4] = {0.f, 0.f, 0.f, 0.f};
    if (ct < 2) {
#pragma unroll
        for (int nt = 0; nt < 4; ++nt) bc1v[nt] = b_c1[ct * 64 + nt * 16 + r];
    }

    for (int nb = walker; nb < N_NODES / 16; nb += nWalk) {
        const int node_r = nb * 16 + r;
        const float* zp = z + (size_t)node_r * 128;
        f32x4 acc[4] = {};
#pragma unroll
        for (int kk = 0; kk < 4; ++kk) {
            const int k0 = kk * 32 + g * 8;
            float4 z0 = *reinterpret_cast<const float4*>(zp + k0);
            float4 z1 = *reinterpret_cast<const float4*>(zp + k0 + 4);
            f16x8 a = pack8(z0, z1);
            if (ct == 0)   // fused Zh store: f16(z[node_r][k0..k0+8])
                *reinterpret_cast<f16x8*>(P + (size_t)node_r * PROW + 384 + k0) = a;
#pragma unroll
            for (int nt = 0; nt < 4; ++nt) mfma16(acc[nt], a, bw[nt][kk]);
        }
#pragma unroll
        for (int nt = 0; nt < 4; ++nt) {
#pragma unroll
            for (int rr = 0; rr < 4; ++rr) {
                const int node = nb * 16 + g * 4 + rr;
                const int col = ct * 64 + nt * 16 + r;
                P[(size_t)node * PROW + col] = (_Float16)(acc[nt][rr] + bc1v[nt]);
            }
        }
    }
}

// ---------------- counting sort by dst ----------------
__global__ __launch_bounds__(256) void zero_kernel(int* __restrict__ counts) {
    const int i = blockIdx.x * 256 + threadIdx.x;
    if (i < N_NODES) counts[i] = 0;
}
__global__ __launch_bounds__(256) void hist_kernel(const int* __restrict__ edge,
                                                   int* __restrict__ counts) {
    for (int e = blockIdx.x * 256 + threadIdx.x; e < N_EDGES; e += gridDim.x * 256)
        atomicAdd(&counts[edge[2 * e + 1]], 1);
}
__global__ __launch_bounds__(1024) void scanA_kernel(const int* __restrict__ counts,
                                                     int* __restrict__ offs,
                                                     int* __restrict__ bsum) {
    __shared__ int buf[1024];
    const int tid = threadIdx.x;
    const int i = blockIdx.x * 1024 + tid;
    const int v = (i < N_NODES) ? counts[i] : 0;
    buf[tid] = v;
    __syncthreads();
    for (int off = 1; off < 1024; off <<= 1) {
        const int t = (tid >= off) ? buf[tid - off] : 0;
        __syncthreads();
        buf[tid] += t;
        __syncthreads();
    }
    if (i < N_NODES) offs[i] = buf[tid] - v;   // exclusive within block
    if (tid == 1023) bsum[blockIdx.x] = buf[1023];
}
// wave-parallel exclusive scan of nblk (<=128) block sums: 2 chunks of 64 + carry
__global__ __launch_bounds__(64) void scanB_kernel(int* __restrict__ bsum, int nblk) {
    const int lane = threadIdx.x;
    int carry = 0;
    for (int c0 = 0; c0 < nblk; c0 += 64) {
        const int i = c0 + lane;
        int v = (i < nblk) ? bsum[i] : 0;
        int s = v;
#pragma unroll
        for (int m = 1; m < 64; m <<= 1) {
            int t = __shfl_up(s, m, 64);
            if (lane >= m) s += t;
        }
        if (i < nblk) bsum[i] = carry + s - v;   // exclusive
        carry += __shfl(s, 63, 64);
    }
}
__global__ __launch_bounds__(1024) void scanC_kernel(int* __restrict__ offs,
                                                     const int* __restrict__ bsum) {
    const int i = blockIdx.x * 1024 + threadIdx.x;
    if (i < N_NODES) offs[i] += bsum[blockIdx.x];
}
__global__ __launch_bounds__(256) void scatter_kernel(const int* __restrict__ edge,
                                                      int* __restrict__ offs,
                                                      int2* __restrict__ sE,
                                                      int* __restrict__ sOrig) {
    for (int e = blockIdx.x * 256 + threadIdx.x; e < N_EDGES; e += gridDim.x * 256) {
        const int s = edge[2 * e], d = edge[2 * e + 1];
        const int pos = atomicAdd(&offs[d], 1);
        sE[pos] = make_int2(s, d);
        sOrig[pos] = e;
    }
}

// ---------------- main edge kernel: 16 edges/wave, unified lane layout ----------------
// lane = g*16 + r : edge = b*16 + r, k-slice = {kk*32 + g*8 .. +8} for kk=0..3.
// Contiguous per-wave chunks preserve dst-sorted locality. orig==null -> identity.
__global__ __launch_bounds__(256) void edge_kernel(
    const int2* __restrict__ eArr, const int* __restrict__ orig,
    const _Float16* __restrict__ P,
    const float* __restrict__ w_h1, const float* __restrict__ b_h1,
    const float* __restrict__ w_h2, const float* __restrict__ b_h2,
    const float* __restrict__ w_c2, const float* __restrict__ b_c2,
    const float* __restrict__ b_b, const float* __restrict__ sw,
    float* __restrict__ out)
{
    __shared__ f16x8 bwlds[1024];   // W_h1 B-fragments: idx=(nt*4+kk)*64 + g*16 + r

    const int tid = threadIdx.x;
    for (int e = tid; e < 1024; e += 256) {
        const int r_ = e & 15, g_ = (e >> 4) & 3, kkf = (e >> 6) & 3, ntf = e >> 8;
        const float* wr = w_h1 + (size_t)(ntf * 16 + r_) * 128 + kkf * 32 + g_ * 8;
        float4 f0 = *reinterpret_cast<const float4*>(wr);
        float4 f1 = *reinterpret_cast<const float4*>(wr + 4);
        bwlds[e] = pack8(f0, f1);
    }
    __syncthreads();

    const int lane = tid & 63;
    const int r = lane & 15, g = lane >> 4;

    const float s0 = sw[0], s1 = sw[1], s2 = sw[2];
    const float mx = fmaxf(s0, fmaxf(s1, s2));
    const float e0 = __expf(s0 - mx), e1 = __expf(s1 - mx), e2 = __expf(s2 - mx);
    const float inv = 1.0f / (e0 + e1 + e2);
    const float W0 = e0 * inv, W1 = e1 * inv, W2 = e2 * inv;
    const float cbias = W0 * b_h2[0] + W1 * b_c2[0] + W2 * b_b[0];

    float bh1v[4], wh2v[4];
#pragma unroll
    for (int nt = 0; nt < 4; ++nt) {
        bh1v[nt] = b_h1[nt * 16 + r];
        wh2v[nt] = w_h2[nt * 16 + r] * W0;   // W0 folded
    }
    f16x8 wc2r[4];
#pragma unroll
    for (int kk = 0; kk < 4; ++kk) {
        const int k0 = kk * 32 + g * 8;
        float4 f0 = *reinterpret_cast<const float4*>(w_c2 + k0);
        float4 f1 = *reinterpret_cast<const float4*>(w_c2 + k0 + 4);
        f0.x *= W1; f0.y *= W1; f0.z *= W1; f0.w *= W1;
        f1.x *= W1; f1.y *= W1; f1.z *= W1; f1.w *= W1;
        wc2r[kk] = pack8(f0, f1);   // W1 folded
    }
    const f16x8* myb = bwlds + g * 16 + r;

    const int gwid = (blockIdx.x * blockDim.x + tid) >> 6;
    const int nW = (gridDim.x * blockDim.x) >> 6;
    const int per = (NB + nW - 1) / nW;
    const int b0 = gwid * per;
    const int b1 = min(b0 + per, NB);
    const int rsel = r & 3;
    const int srcl = ((r >> 2) << 4) | r;

    int b = b0;
    int2 sd = make_int2(0, 0);
    int ov = 0;
    if (b < b1) {
        sd = eArr[b * 16 + r];
        ov = orig ? orig[b * 16 + r] : b * 16 + r;
    }

    for (; b < b1; ++b) {
        int2 sdn = sd; int ovn = ov;
        if (b + 1 < b1) {
            sdn = eArr[(b + 1) * 16 + r];
            ovn = orig ? orig[(b + 1) * 16 + r] : (b + 1) * 16 + r;
        }

        const _Float16* ps = P + (size_t)sd.x * PROW;
        const _Float16* pd = P + (size_t)sd.y * PROW;

        // issue all 20 gathers up front (2 bases, static offsets)
        f16x8 av[4], bv[4], yv[4], zs[4], zd[4];
#pragma unroll
        for (int kk = 0; kk < 4; ++kk) {
            const int off = kk * 32 + g * 8;
            av[kk] = *reinterpret_cast<const f16x8*>(ps + off);         // A'[src]
            bv[kk] = *reinterpret_cast<const f16x8*>(pd + 128 + off);   // B[dst]
            yv[kk] = *reinterpret_cast<const f16x8*>(pd + 256 + off);   // Y[dst]
            zs[kk] = *reinterpret_cast<const f16x8*>(ps + 384 + off);   // Zh[src]
            zd[kk] = *reinterpret_cast<const f16x8*>(pd + 384 + off);   // Zh[dst]
        }

        // score1 via MFMA
        f32x4 acc[4] = {};
#pragma unroll
        for (int kk = 0; kk < 4; ++kk) {
            f16x8 a = zs[kk] * zd[kk];
            mfma16(acc[0], a, myb[(0 * 4 + kk) * 64]);
            mfma16(acc[1], a, myb[(1 * 4 + kk) * 64]);
            mfma16(acc[2], a, myb[(2 * 4 + kk) * 64]);
            mfma16(acc[3], a, myb[(3 * 4 + kk) * 64]);
        }
        float t4[4];
#pragma unroll
        for (int rr = 0; rr < 4; ++rr) {
            float s = 0.f;
#pragma unroll
            for (int nt = 0; nt < 4; ++nt)
                s = fmaf(fmaxf(acc[nt][rr] + bh1v[nt], 0.f), wh2v[nt], s);
            t4[rr] = s;
        }
#pragma unroll
        for (int mask = 1; mask <= 8; mask <<= 1) {
#pragma unroll
            for (int rr = 0; rr < 4; ++rr)
                t4[rr] += __shfl_xor(t4[rr], mask, 16);
        }
        float u = t4[0];
        if (rsel == 1) u = t4[1];
        if (rsel == 2) u = t4[2];
        if (rsel == 3) u = t4[3];
        const float sc1w = __shfl(u, srcl, 64);

        // score2 & score3
        float sA = 0.f, sB = 0.f;
#pragma unroll
        for (int kk = 0; kk < 4; ++kk) {
            f16x8 s = av[kk] + bv[kk];
            s = __builtin_elementwise_max(s, (f16x8)(_Float16)0.f);
#pragma unroll
            for (int j2 = 0; j2 < 4; ++j2) {
                sA = fdot2(s, wc2r[kk], j2, sA);
                sB = fdot2(zs[kk], yv[kk], j2, sB);
            }
        }
        sA += __shfl_xor(sA, 16, 64);
        sA += __shfl_xor(sA, 32, 64);
        sB += __shfl_xor(sB, 16, 64);
        sB += __shfl_xor(sB, 32, 64);

        const float res = sc1w + sA + fmaf(W2, sB, cbias);
        if (lane < 16) out[ov] = res;
        sd = sdn; ov = ovn;
    }
}

// ---------------- fallback: fused wave-per-edge, no workspace ----------------
__global__ __launch_bounds__(256) void fused_fallback(
    const float* __restrict__ z, const int* __restrict__ edge,
    const float* __restrict__ w_h1, const float* __restrict__ b_h1,
    const float* __restrict__ w_h2, const float* __restrict__ b_h2,
    const float* __restrict__ w_c1, const float* __restrict__ b_c1,
    const float* __restrict__ w_c2, const float* __restrict__ b_c2,
    const float* __restrict__ w_b, const float* __restrict__ b_b,
    const float* __restrict__ sw, float* __restrict__ out)
{
    __shared__ float zbuf[4][256];
    const int lane = threadIdx.x & 63;
    const int w = threadIdx.x >> 6;
    const int gw = blockIdx.x * 4 + w;
    const int nw = gridDim.x * 4;

    const float s0 = sw[0], s1 = sw[1], s2 = sw[2];
    const float mx = fmaxf(s0, fmaxf(s1, s2));
    const float e0 = __expf(s0 - mx), e1 = __expf(s1 - mx), e2 = __expf(s2 - mx);
    const float inv = 1.0f / (e0 + e1 + e2);
    const float W0 = e0 * inv, W1 = e1 * inv, W2 = e2 * inv;
    const float cbias = W0 * b_h2[0] + W1 * b_c2[0] + W2 * b_b[0];

    for (int e = gw; e < N_EDGES; e += nw) {
        const int src = edge[2 * e], dst = edge[2 * e + 1];
        const float zs0 = z[(size_t)src * 128 + lane];
        const float zs1 = z[(size_t)src * 128 + 64 + lane];
        const float zd0 = z[(size_t)dst * 128 + lane];
        const float zd1 = z[(size_t)dst * 128 + 64 + lane];
        zbuf[w][lane] = zs0; zbuf[w][64 + lane] = zs1;
        zbuf[w][128 + lane] = zd0; zbuf[w][192 + lane] = zd1;
        asm volatile("s_waitcnt lgkmcnt(0)" ::: "memory");

        float h = 0.f;
        const float* whr = w_h1 + (size_t)lane * 128;
        for (int d = 0; d < 128; ++d)
            h = fmaf(zbuf[w][d] * zbuf[w][128 + d], whr[d], h);
        float sc1 = fmaxf(h + b_h1[lane], 0.f) * w_h2[lane];

        float c0 = 0.f, c1 = 0.f;
        const float* w0r = w_c1 + (size_t)lane * 256;
        const float* w1r = w_c1 + (size_t)(lane + 64) * 256;
        for (int d = 0; d < 256; ++d) {
            const float cat = zbuf[w][d];
            c0 = fmaf(cat, w0r[d], c0);
            c1 = fmaf(cat, w1r[d], c1);
        }
        float sc2 = fmaxf(c0 + b_c1[lane], 0.f) * w_c2[lane]
                  + fmaxf(c1 + b_c1[lane + 64], 0.f) * w_c2[lane + 64];

        float t0 = 0.f, t1 = 0.f;
        const float* wb0 = w_b + (size_t)lane * 128;
        const float* wb1 = w_b + (size_t)(lane + 64) * 128;
        for (int f = 0; f < 128; ++f) {
            const float zdf = zbuf[w][128 + f];
            t0 = fmaf(wb0[f], zdf, t0);
            t1 = fmaf(wb1[f], zdf, t1);
        }
        float sc3 = zs0 * t0 + zs1 * t1;

        float v = fmaf(W0, sc1, fmaf(W1, sc2, W2 * sc3));
#pragma unroll
        for (int m = 1; m < 64; m <<= 1) v += __shfl_xor(v, m, 64);
        if (lane == 0) out[e] = v + cbias;
    }
}

extern "C" void kernel_launch(void* const* d_in, const int* in_sizes, int n_in,
                              void* d_out, int out_size, void* d_ws, size_t ws_size,
                              hipStream_t stream)
{
    const float* z    = (const float*)d_in[0];
    const int*   edge = (const int*)d_in[1];
    const float* w_h1 = (const float*)d_in[2];
    const float* b_h1 = (const float*)d_in[3];
    const float* w_h2 = (const float*)d_in[4];
    const float* b_h2 = (const float*)d_in[5];
    const float* w_c1 = (const float*)d_in[6];
    const float* b_c1 = (const float*)d_in[7];
    const float* w_c2 = (const float*)d_in[8];
    const float* b_c2 = (const float*)d_in[9];
    const float* w_b  = (const float*)d_in[10];
    const float* b_b  = (const float*)d_in[11];
    const float* sw   = (const float*)d_in[12];
    float* outp = (float*)d_out;

    // ws layout
    const size_t szP     = (size_t)N_NODES * PROW * sizeof(_Float16);  // 102,400,000
    const size_t szCnt   = (size_t)N_NODES * sizeof(int);              //     400,000
    const size_t szBsum  = 512;
    const size_t szSE    = (size_t)N_EDGES * sizeof(int2);             //   8,000,000
    const size_t szSO    = (size_t)N_EDGES * sizeof(int);              //   4,000,000
    const size_t needP    = szP;
    const size_t needSort = szP + 2 * szCnt + szBsum + szSE + szSO;    // ~115.2 MB

    if (ws_size >= needP) {
        char* wsb = (char*)d_ws;
        _Float16* P = (_Float16*)wsb;
        hipLaunchKernelGGL(precomp_kernel, dim3(2048), dim3(256), 0, stream,
                           z, w_c1, b_c1, w_b, P);
        if (ws_size >= needSort) {
            int*  counts = (int*)(wsb + szP);
            int*  offs   = (int*)(wsb + szP + szCnt);
            int*  bsum   = (int*)(wsb + szP + 2 * szCnt);
            int2* sE     = (int2*)(wsb + szP + 2 * szCnt + szBsum);
            int*  sOrig  = (int*)(wsb + szP + 2 * szCnt + szBsum + szSE);
            const int nblk = (N_NODES + 1023) / 1024;   // 98
            hipLaunchKernelGGL(zero_kernel, dim3((N_NODES + 255) / 256), dim3(256),
                               0, stream, counts);
            hipLaunchKernelGGL(hist_kernel, dim3(2048), dim3(256), 0, stream,
                               edge, counts);
            hipLaunchKernelGGL(scanA_kernel, dim3(nblk), dim3(1024), 0, stream,
                               counts, offs, bsum);
            hipLaunchKernelGGL(scanB_kernel, dim3(1), dim3(64), 0, stream, bsum, nblk);
            hipLaunchKernelGGL(scanC_kernel, dim3(nblk), dim3(1024), 0, stream,
                               offs, bsum);
            hipLaunchKernelGGL(scatter_kernel, dim3(2048), dim3(256), 0, stream,
                               edge, offs, sE, sOrig);
            hipLaunchKernelGGL(edge_kernel, dim3(1024), dim3(256), 0, stream,
                               sE, sOrig, P, w_h1, b_h1, w_h2, b_h2, w_c2, b_c2,
                               b_b, sw, outp);
        } else {
            hipLaunchKernelGGL(edge_kernel, dim3(1024), dim3(256), 0, stream,
                               (const int2*)edge, (const int*)nullptr, P,
                               w_h1, b_h1, w_h2, b_h2, w_c2, b_c2, b_b, sw, outp);
        }
    } else {
        hipLaunchKernelGGL(fused_fallback, dim3(4096), dim3(256), 0, stream,
                           z, edge, w_h1, b_h1, w_h2, b_h2, w_c1, b_c1,
                           w_c2, b_c2, w_b, b_b, sw, outp);
    }
}